// Round 4
// baseline (273.199 us; speedup 1.0000x reference)
//
#include <hip/hip_runtime.h>

#define EPS 1e-5f

typedef __attribute__((ext_vector_type(8))) short short8;
typedef __attribute__((ext_vector_type(4))) float float4v;

__device__ inline unsigned short f2bf(float f) {
  unsigned u = __float_as_uint(f);
  unsigned r = (u + 0x7fffu + ((u >> 16) & 1u)) >> 16;
  return (unsigned short)r;
}
__device__ inline uint pk2(float a, float b) {
  return (uint)f2bf(a) | ((uint)f2bf(b) << 16);
}

// ---------------------------------------------------------------------------
// xform: fold BN scale into weights + (fused) both bias vectors.
//  - Awt bf16 [kc(18)][mt(8)][q(4)][ml(16)][j(8)] (A-fragment-ready, e pad 128)
//  - Wc fp32 [ci(64)][co(64)] transposed compress weights * inv[co].
//  - bias2[128], bias_c[64] (former bias_kernel, folded into the tail)
// ---------------------------------------------------------------------------
__global__ __launch_bounds__(256) void xform_kernel(
    const float* __restrict__ enc_w, const float* __restrict__ enc_gamma,
    const float* __restrict__ enc_var, const float* __restrict__ comp_w,
    const float* __restrict__ comp_gamma, const float* __restrict__ comp_var,
    const float* __restrict__ enc_b, const float* __restrict__ enc_beta,
    const float* __restrict__ enc_mean, const float* __restrict__ comp_beta,
    const float* __restrict__ comp_mean, ushort* __restrict__ Awt,
    float* __restrict__ Wc, float* __restrict__ bias2,
    float* __restrict__ bias_c) {
  int u = blockIdx.x * 256 + threadIdx.x;
  if (u < 9216) {
    int kc = u >> 9, rem = u & 511;
    int mt = rem >> 6, q = (rem >> 4) & 3, ml = rem & 15;
    int e = mt * 16 + ml;
    int t = kc >> 1, h = kc & 1;
    int dy = t / 3, dx = t - dy * 3;
    float inv = (e < 100) ? enc_gamma[e] * rsqrtf(enc_var[e] + EPS) : 0.f;
    ushort o[8];
#pragma unroll
    for (int j = 0; j < 8; ++j) {
      int ci = h * 32 + q * 8 + j;
      float w = (e < 100) ? enc_w[(e * 64 + ci) * 9 + dy * 3 + dx] * inv : 0.f;
      o[j] = f2bf(w);
    }
    uint4 v;
    v.x = (uint)o[0] | ((uint)o[1] << 16);
    v.y = (uint)o[2] | ((uint)o[3] << 16);
    v.z = (uint)o[4] | ((uint)o[5] << 16);
    v.w = (uint)o[6] | ((uint)o[7] << 16);
    *reinterpret_cast<uint4*>(Awt + (size_t)u * 8) = v;
  } else if (u < 13312) {
    int v = u - 9216;
    int co = v & 63;
    float inv = comp_gamma[co] * rsqrtf(comp_var[co] + EPS);
    Wc[v] = comp_w[co * 64 + (v >> 6)] * inv;
  } else if (u < 13440) {
    int t = u - 13312;
    float v = 0.f;
    if (t < 100) {
      float inv = enc_gamma[t] * rsqrtf(enc_var[t] + EPS);
      v = enc_b[t] * inv + enc_beta[t] - enc_mean[t] * inv;
    }
    bias2[t] = v;
  } else if (u < 13504) {
    int c = u - 13440;
    float inv = comp_gamma[c] * rsqrtf(comp_var[c] + EPS);
    bias_c[c] = comp_beta[c] - comp_mean[c] * inv;
  }
}

// ---------------------------------------------------------------------------
// compress: 1x1 conv 64->64 + BN + ReLU -> Wm1t bf16 pixel-major, plus
// Xb bf16 pixel-major. Block = 64 consecutive pixels, 1024 blocks (4/CU).
// X staged in LDS [64px][65] (conflict-free in & out). Wave w computes
// co=[16w,16w+16) for its lane's pixel; weight/bias addresses are forced
// wave-uniform via readfirstlane -> s_load (scalar pipe). Both outputs
// bounce through LDS and leave as fully-coalesced uint4 streams.
// ---------------------------------------------------------------------------
__global__ __launch_bounds__(256) void compress_kernel(
    const float* __restrict__ X, const float* __restrict__ Wc,
    const float* __restrict__ bias_c, ushort* __restrict__ out,
    ushort* __restrict__ Xb) {
  __shared__ __align__(16) float xtile[64 * 65];
  __shared__ __align__(16) float osm[64 * 68];
  const int tid = threadIdx.x;
  const int p0 = blockIdx.x * 64;
  const int b = p0 >> 14;
  const float* xbase = X + ((size_t)b << 20) + (p0 & 16383);

#pragma unroll
  for (int k = 0; k < 16; ++k) {
    int u = k * 256 + tid;
    int ci = u >> 6, px = u & 63;      // wave: ci fixed, px 0..63 -> coalesced
    xtile[px * 65 + ci] = xbase[((size_t)ci << 14) + px];
  }
  __syncthreads();

  const int wv = __builtin_amdgcn_readfirstlane(tid >> 6);
  const int ln = tid & 63;
  float acc[16];
#pragma unroll
  for (int u = 0; u < 16; ++u) acc[u] = bias_c[wv * 16 + u];
  const float* xr = xtile + ln * 65;
#pragma unroll 8
  for (int ci = 0; ci < 64; ++ci) {
    float xv = xr[ci];
    const float* wr = Wc + ci * 64 + wv * 16;   // wave-uniform -> s_load
#pragma unroll
    for (int u = 0; u < 16; ++u) acc[u] = fmaf(wr[u], xv, acc[u]);
  }
  float4v* orow = reinterpret_cast<float4v*>(osm) + ln * 17 + wv * 4;
#pragma unroll
  for (int j = 0; j < 4; ++j) {
    float4v t;
#pragma unroll
    for (int s = 0; s < 4; ++s) t[s] = fmaxf(acc[j * 4 + s], 0.f);
    orow[j] = t;                        // stride-17 float4 -> conflict-free
  }
  __syncthreads();

#pragma unroll
  for (int j = 0; j < 2; ++j) {
    int u = j * 256 + tid;
    int px = u >> 3, g = u & 7;
    const float* so = osm + px * 68 + g * 8;
    uint4 vo = make_uint4(pk2(so[0], so[1]), pk2(so[2], so[3]),
                          pk2(so[4], so[5]), pk2(so[6], so[7]));
    *reinterpret_cast<uint4*>(out + (size_t)(p0 + px) * 64 + g * 8) = vo;
    const float* sx = xtile + px * 65 + g * 8;
    uint4 vx = make_uint4(pk2(sx[0], sx[1]), pk2(sx[2], sx[3]),
                          pk2(sx[4], sx[5]), pk2(sx[6], sx[7]));
    *reinterpret_cast<uint4*>(Xb + (size_t)(p0 + px) * 64 + g * 8) = vx;
  }
}

// ---------------------------------------------------------------------------
// encode+carafe FUSED: 3x3 conv (64->100) implicit GEMM on MFMA + bias +
// softmax(25) + pixel-shuffle de-interleave, weights kept in LDS (never hit
// global), then carafe apply on the same 8x8 lo-res tile.
//
// Round-4 changes (round 3 ran VGPR=256 / 10% occupancy / 4.6M conflicts):
//  - __launch_bounds__(256, 3): cap ~168 regs -> 3 blocks/CU. (Round 2
//    showed cap=128 spills; unconstrained takes 256. 168 is the live range.)
//  - phase 6 split into two 16-channel passes (acc2[16] not [32]): peak
//    pressure -32 regs so the cap is spill-safe.
//  - wsm padded to [64][101]: row stride 101 dwords === 5 (mod 32), coprime
//    with 32 -> phase-4 softmax reads (was 8-way conflicted at stride 100)
//    become conflict-free. Phase-3 stores become 4x b32 (pad kills 16B
//    alignment) - negligible.
//
// LDS map (40,192 B total):
//   region0 [0, 25856):  Xt [100 pos][72 ci] bf16 (14.4 KB)
//                     -> wsm [64 px][101] f32   (25.9 KB, after MFMA)
//                     -> xt  [144 pos][72 ch] bf16 (20.7 KB, after softmax)
//   region1 [25856, 40192): wpT [56][64] uint (transposed weight store:
//     column px -> bank px%32; b16 writes at ushort stride 2 and b32 reads
//     at uint stride 1 are both 2-way bank aliases = free)
// ---------------------------------------------------------------------------
__global__ __launch_bounds__(256, 3) void encode_carafe(
    const ushort* __restrict__ Wm1t, const ushort* __restrict__ Awt,
    const float* __restrict__ bias2, const ushort* __restrict__ Xb,
    float* __restrict__ out) {
  __shared__ __align__(16) char smem[40192];
  ushort* Xt = (ushort*)smem;                  // [100 pos (10x10)][72 ci]
  const int tid = threadIdx.x;
  const int b = blockIdx.z;
  const int y0 = blockIdx.y * 8, x0 = blockIdx.x * 8;

  // ---- phase 1: stage compressed features (10x10 halo) ----
  for (int u = tid; u < 800; u += 256) {       // 100 pos x 8 ci-groups
    int pos = u >> 3, cg = u & 7;
    int iy = pos / 10, ix = pos - iy * 10;
    int gy = y0 + iy - 1, gx = x0 + ix - 1;
    uint4 v = make_uint4(0, 0, 0, 0);
    if ((unsigned)gy < 128u && (unsigned)gx < 128u)
      v = *reinterpret_cast<const uint4*>(
          Wm1t + ((((size_t)b << 14) + (gy << 7) + gx) << 6) + cg * 8);
    *reinterpret_cast<uint4*>(&Xt[pos * 72 + cg * 8]) = v;
  }
  __syncthreads();

  // ---- phase 2: implicit-GEMM MFMA over 18 kc slices ----
  const int wave = tid >> 6, lane = tid & 63;
  const int q = lane >> 4, px16 = lane & 15;

  float4v acc[2][4];
#pragma unroll
  for (int a = 0; a < 2; ++a)
#pragma unroll
    for (int n = 0; n < 4; ++n) acc[a][n] = (float4v){0.f, 0.f, 0.f, 0.f};

  const short8* Ap = reinterpret_cast<const short8*>(Awt);
#pragma unroll
  for (int kc = 0; kc < 18; ++kc) {
    const int t = kc >> 1, h = kc & 1;
    const int dy = t / 3, dx = t - dy * 3;
    short8 af[2];
#pragma unroll
    for (int a = 0; a < 2; ++a)
      af[a] = Ap[kc * 512 + (wave * 2 + a) * 64 + lane];
    short8 bfr[4];
#pragma unroll
    for (int n = 0; n < 4; ++n) {
      int p = n * 16 + px16;                  // pixel in 8x8 tile, row-major 8
      int iy = (p >> 3) + dy, ix = (p & 7) + dx;
      bfr[n] = *reinterpret_cast<const short8*>(
          &Xt[(iy * 10 + ix) * 72 + h * 32 + q * 8]);
    }
#pragma unroll
    for (int a = 0; a < 2; ++a)
#pragma unroll
      for (int n = 0; n < 4; ++n)
        acc[a][n] = __builtin_amdgcn_mfma_f32_16x16x32_bf16(
            af[a], bfr[n], acc[a][n], 0, 0, 0);
  }
  __syncthreads();

  // ---- phase 3: accumulators -> wsm (wave w owns e in [32w, 32w+32)) ----
  // wsm row stride 101 (pad): scalar b32 stores (odd stride kills b128
  // alignment); lane->bank spread is ~uniform.
  float* wsm = (float*)smem;                   // [64 px][101]
#pragma unroll
  for (int a = 0; a < 2; ++a) {
    int ebase = (wave * 2 + a) * 16 + q * 4;
    if (ebase < 100) {
#pragma unroll
      for (int n = 0; n < 4; ++n) {
        int p = n * 16 + px16;
        float* dst = wsm + p * 101 + ebase;
        dst[0] = acc[a][n][0];
        dst[1] = acc[a][n][1];
        dst[2] = acc[a][n][2];
        dst[3] = acc[a][n][3];
      }
    }
  }
  __syncthreads();

  // ---- phase 4: bias + softmax(25), one (pixel, component) per thread ----
  // component qd = pixel-shuffle slot; channels are e = 4*tap + qd.
  // wpT row layout (uint [56][64]): row k      = pk2(comp0, comp1) of tap k
  //                                 row 28 + k = pk2(comp2, comp3) of tap k
  // -> thread (px, qd) writes ushort half (qd&1) of row (qd>>1)*28 + k.
  // Read addr = px*101 + qd + 4j: stride 101 === 5 (mod 32), coprime -> the
  // 64 px-lanes cover all banks 2x = conflict-free.
  {
    ushort* wpS = (ushort*)(smem + 25856);     // ushort view of wpT [56][128]
    const int px = tid & 63, qd = tid >> 6;
    const int rowbase = (qd >> 1) * 28;
    const int half = qd & 1;
    const float* wp = wsm + px * 101 + qd;
    float v[25];
#pragma unroll
    for (int j = 0; j < 25; ++j) v[j] = wp[4 * j] + bias2[4 * j + qd];
    float m = v[0];
#pragma unroll
    for (int j = 1; j < 25; ++j) m = fmaxf(m, v[j]);
    float s = 0.f;
#pragma unroll
    for (int j = 0; j < 25; ++j) { v[j] = __expf(v[j] - m); s += v[j]; }
    float inv = 1.f / s;
#pragma unroll
    for (int k = 0; k < 25; ++k)
      wpS[(rowbase + k) * 128 + px * 2 + half] = f2bf(v[k] * inv);
  }
  __syncthreads();

  // ---- phase 5: restage region0 with Xb halo (12x12) for carafe ----
  ushort* xt = (ushort*)smem;                  // [144 pos][72 ch]
  for (int u = tid; u < 1152; u += 256) {      // 144 pos x 8 ch-groups
    int pos = u >> 3, cg = u & 7;
    int iy = pos / 12, ix = pos - iy * 12;
    int gy = y0 + iy - 2, gx = x0 + ix - 2;
    uint4 v = make_uint4(0, 0, 0, 0);
    if ((unsigned)gy < 128u && (unsigned)gx < 128u)
      v = *reinterpret_cast<const uint4*>(
          Xb + (((size_t)b * 16384 + gy * 128 + gx) << 6) + cg * 8);
    *reinterpret_cast<uint4*>(&xt[pos * 72 + cg * 8]) = v;
  }
  __syncthreads();

  // ---- phase 6: carafe apply, two 16-channel passes (acc2[16] each) ----
  {
    uint* wpT = (uint*)(smem + 25856);         // [56 rows][64 px]
    const int p = tid & 63, qq = tid >> 6;
    const int r1 = qq & 1, cq = qq >> 1;
    const int py = p >> 3, pxl = p & 7;
    const uint* wrow = wpT + r1 * 28 * 64 + p;
    const int yq = (y0 + py) * 2 + r1;
    const int xq = (x0 + pxl) * 2;

#pragma unroll
    for (int h = 0; h < 2; ++h) {              // channel half within cq group
      float2 acc2[16];
#pragma unroll
      for (int i = 0; i < 16; ++i) acc2[i] = make_float2(0.f, 0.f);

#pragma unroll
      for (int k = 0; k < 25; ++k) {
        const int dy = k / 5, dx = k - dy * 5;
        const ushort* bp =
            xt + ((py + dy) * 12 + (pxl + dx)) * 72 + cq * 32 + h * 16;
        uint wk = wrow[k * 64];
        float w0 = __uint_as_float(wk << 16);
        float w1 = __uint_as_float(wk & 0xffff0000u);
#pragma unroll
        for (int j = 0; j < 2; ++j) {
          uint4 xv = *reinterpret_cast<const uint4*>(bp + 8 * j);
          const uint xu[4] = {xv.x, xv.y, xv.z, xv.w};
#pragma unroll
          for (int t = 0; t < 4; ++t) {
            float xlo = __uint_as_float(xu[t] << 16);
            float xhi = __uint_as_float(xu[t] & 0xffff0000u);
            int c = j * 8 + t * 2;
            acc2[c].x = fmaf(w0, xlo, acc2[c].x);
            acc2[c].y = fmaf(w1, xlo, acc2[c].y);
            acc2[c + 1].x = fmaf(w0, xhi, acc2[c + 1].x);
            acc2[c + 1].y = fmaf(w1, xhi, acc2[c + 1].y);
          }
        }
      }

#pragma unroll
      for (int ci = 0; ci < 16; ++ci) {
        int c = cq * 32 + h * 16 + ci;
        *reinterpret_cast<float2*>(
            out + ((size_t)(b * 64 + c) * 256 + yq) * 256 + xq) = acc2[ci];
      }
    }
  }
}

// ---------------------------------------------------------------------------
extern "C" void kernel_launch(void* const* d_in, const int* in_sizes, int n_in,
                              void* d_out, int out_size, void* d_ws, size_t ws_size,
                              hipStream_t stream) {
  const float* X          = (const float*)d_in[0];
  const float* comp_w     = (const float*)d_in[1];
  const float* comp_gamma = (const float*)d_in[2];
  const float* comp_beta  = (const float*)d_in[3];
  const float* comp_mean  = (const float*)d_in[4];
  const float* comp_var   = (const float*)d_in[5];
  const float* enc_w      = (const float*)d_in[6];
  const float* enc_b      = (const float*)d_in[7];
  const float* enc_gamma  = (const float*)d_in[8];
  const float* enc_beta   = (const float*)d_in[9];
  const float* enc_mean   = (const float*)d_in[10];
  const float* enc_var    = (const float*)d_in[11];
  float* out = (float*)d_out;

  char* ws = (char*)d_ws;
  ushort* Wm1t  = (ushort*)(ws);                    //  8,388,608 B
  ushort* Xb    = (ushort*)(ws + 8388608);          //  8,388,608 B
  ushort* Awt   = (ushort*)(ws + 16777216);         //    147,456 B
  float*  Wc    = (float*)(ws + 16924672);          //     16,384 B
  float*  bias2 = (float*)(ws + 16941056);          //        512 B
  float*  biasc = (float*)(ws + 16941568);          //        256 B

  xform_kernel<<<53, 256, 0, stream>>>(enc_w, enc_gamma, enc_var,
                                       comp_w, comp_gamma, comp_var,
                                       enc_b, enc_beta, enc_mean,
                                       comp_beta, comp_mean,
                                       Awt, Wc, bias2, biasc);
  compress_kernel<<<1024, 256, 0, stream>>>(X, Wc, biasc, Wm1t, Xb);
  encode_carafe<<<dim3(16, 16, 4), 256, 0, stream>>>(Wm1t, Awt, bias2, Xb, out);
}

// Round 5
// 142.293 us; speedup vs baseline: 1.9200x; 1.9200x over previous
//
#include <hip/hip_runtime.h>

#define EPS 1e-5f

typedef __attribute__((ext_vector_type(8))) short short8;
typedef __attribute__((ext_vector_type(4))) float float4v;

__device__ inline unsigned short f2bf(float f) {
  unsigned u = __float_as_uint(f);
  unsigned r = (u + 0x7fffu + ((u >> 16) & 1u)) >> 16;
  return (unsigned short)r;
}
__device__ inline uint pk2(float a, float b) {
  return (uint)f2bf(a) | ((uint)f2bf(b) << 16);
}

// ---------------------------------------------------------------------------
// xform: fold BN scale into weights + both bias vectors.
//  - Awt bf16 [kc(18)][mt(8)][q(4)][ml(16)][j(8)] (A-fragment-ready, e pad 128)
//  - Wc fp32 [ci(64)][co(64)] transposed compress weights * inv[co].
//  - bias2[128], bias_c[64]
// ---------------------------------------------------------------------------
__global__ __launch_bounds__(256) void xform_kernel(
    const float* __restrict__ enc_w, const float* __restrict__ enc_gamma,
    const float* __restrict__ enc_var, const float* __restrict__ comp_w,
    const float* __restrict__ comp_gamma, const float* __restrict__ comp_var,
    const float* __restrict__ enc_b, const float* __restrict__ enc_beta,
    const float* __restrict__ enc_mean, const float* __restrict__ comp_beta,
    const float* __restrict__ comp_mean, ushort* __restrict__ Awt,
    float* __restrict__ Wc, float* __restrict__ bias2,
    float* __restrict__ bias_c) {
  int u = blockIdx.x * 256 + threadIdx.x;
  if (u < 9216) {
    int kc = u >> 9, rem = u & 511;
    int mt = rem >> 6, q = (rem >> 4) & 3, ml = rem & 15;
    int e = mt * 16 + ml;
    int t = kc >> 1, h = kc & 1;
    int dy = t / 3, dx = t - dy * 3;
    float inv = (e < 100) ? enc_gamma[e] * rsqrtf(enc_var[e] + EPS) : 0.f;
    ushort o[8];
#pragma unroll
    for (int j = 0; j < 8; ++j) {
      int ci = h * 32 + q * 8 + j;
      float w = (e < 100) ? enc_w[(e * 64 + ci) * 9 + dy * 3 + dx] * inv : 0.f;
      o[j] = f2bf(w);
    }
    uint4 v;
    v.x = (uint)o[0] | ((uint)o[1] << 16);
    v.y = (uint)o[2] | ((uint)o[3] << 16);
    v.z = (uint)o[4] | ((uint)o[5] << 16);
    v.w = (uint)o[6] | ((uint)o[7] << 16);
    *reinterpret_cast<uint4*>(Awt + (size_t)u * 8) = v;
  } else if (u < 13312) {
    int v = u - 9216;
    int co = v & 63;
    float inv = comp_gamma[co] * rsqrtf(comp_var[co] + EPS);
    Wc[v] = comp_w[co * 64 + (v >> 6)] * inv;
  } else if (u < 13440) {
    int t = u - 13312;
    float v = 0.f;
    if (t < 100) {
      float inv = enc_gamma[t] * rsqrtf(enc_var[t] + EPS);
      v = enc_b[t] * inv + enc_beta[t] - enc_mean[t] * inv;
    }
    bias2[t] = v;
  } else if (u < 13504) {
    int c = u - 13440;
    float inv = comp_gamma[c] * rsqrtf(comp_var[c] + EPS);
    bias_c[c] = comp_beta[c] - comp_mean[c] * inv;
  }
}

// ---------------------------------------------------------------------------
// compress: 1x1 conv 64->64 + BN + ReLU -> Wm1t bf16 pixel-major, plus
// Xb bf16 pixel-major. Block = 64 consecutive pixels, 1024 blocks (4/CU).
// (unchanged, round-0 verified)
// ---------------------------------------------------------------------------
__global__ __launch_bounds__(256) void compress_kernel(
    const float* __restrict__ X, const float* __restrict__ Wc,
    const float* __restrict__ bias_c, ushort* __restrict__ out,
    ushort* __restrict__ Xb) {
  __shared__ __align__(16) float xtile[64 * 65];
  __shared__ __align__(16) float osm[64 * 68];
  const int tid = threadIdx.x;
  const int p0 = blockIdx.x * 64;
  const int b = p0 >> 14;
  const float* xbase = X + ((size_t)b << 20) + (p0 & 16383);

#pragma unroll
  for (int k = 0; k < 16; ++k) {
    int u = k * 256 + tid;
    int ci = u >> 6, px = u & 63;      // wave: ci fixed, px 0..63 -> coalesced
    xtile[px * 65 + ci] = xbase[((size_t)ci << 14) + px];
  }
  __syncthreads();

  const int wv = __builtin_amdgcn_readfirstlane(tid >> 6);
  const int ln = tid & 63;
  float acc[16];
#pragma unroll
  for (int u = 0; u < 16; ++u) acc[u] = bias_c[wv * 16 + u];
  const float* xr = xtile + ln * 65;
#pragma unroll 8
  for (int ci = 0; ci < 64; ++ci) {
    float xv = xr[ci];
    const float* wr = Wc + ci * 64 + wv * 16;   // wave-uniform -> s_load
#pragma unroll
    for (int u = 0; u < 16; ++u) acc[u] = fmaf(wr[u], xv, acc[u]);
  }
  float4v* orow = reinterpret_cast<float4v*>(osm) + ln * 17 + wv * 4;
#pragma unroll
  for (int j = 0; j < 4; ++j) {
    float4v t;
#pragma unroll
    for (int s = 0; s < 4; ++s) t[s] = fmaxf(acc[j * 4 + s], 0.f);
    orow[j] = t;                        // stride-17 float4 -> conflict-free
  }
  __syncthreads();

#pragma unroll
  for (int j = 0; j < 2; ++j) {
    int u = j * 256 + tid;
    int px = u >> 3, g = u & 7;
    const float* so = osm + px * 68 + g * 8;
    uint4 vo = make_uint4(pk2(so[0], so[1]), pk2(so[2], so[3]),
                          pk2(so[4], so[5]), pk2(so[6], so[7]));
    *reinterpret_cast<uint4*>(out + (size_t)(p0 + px) * 64 + g * 8) = vo;
    const float* sx = xtile + px * 65 + g * 8;
    uint4 vx = make_uint4(pk2(sx[0], sx[1]), pk2(sx[2], sx[3]),
                          pk2(sx[4], sx[5]), pk2(sx[6], sx[7]));
    *reinterpret_cast<uint4*>(Xb + (size_t)(p0 + px) * 64 + g * 8) = vx;
  }
}

// ---------------------------------------------------------------------------
// encode: 3x3 conv (64->100) implicit GEMM on MFMA + bias + softmax(25) +
// pixel-shuffle de-interleave + bf16 pack. 8x8 px tile, 1024 blocks.
// UNFUSED again (rounds 1-4 showed the fused kernel has no good VGPR
// operating point: unbounded -> 256 regs / 2 blocks/CU; any cap -> the
// allocator halves into VGPR/AGPR and spills). Banked improvements:
//  - scalar parallel softmax over all 256 threads (R2 math, verified):
//    peak state 25 floats/thread, no idle waves -> natural VGPR well
//    under the 256 cliff.
//  - wsm stride 101 (R4, verified): softmax reads conflict-free.
//  - Wtu stored TILE-MAJOR [tile][56 rows][64 px]: softmax packs into the
//    wpT LDS transpose (2-way aliases = free), which then streams out as
//    fully-coalesced uint4; carafe reads it back coalesced too.
// LDS 25,856 B total (wpT overlays dead wsm after a barrier) -> 6 blk/CU.
// ---------------------------------------------------------------------------
__global__ __launch_bounds__(256) void encode_mfma(
    const ushort* __restrict__ Wm1t, const ushort* __restrict__ Awt,
    const float* __restrict__ bias2, uint* __restrict__ Wtu) {
  __shared__ __align__(16) char smem[25856];   // Xt 14400 -> wsm 25856 -> wpT
  ushort* Xt = (ushort*)smem;                  // [100 pos (10x10)][72 ci]
  const int tid = threadIdx.x;
  const int b = blockIdx.z;
  const int y0 = blockIdx.y * 8, x0 = blockIdx.x * 8;

  // ---- phase 1: stage compressed features (10x10 halo) ----
  for (int u = tid; u < 800; u += 256) {       // 100 pos x 8 ci-groups
    int pos = u >> 3, cg = u & 7;
    int iy = pos / 10, ix = pos - iy * 10;
    int gy = y0 + iy - 1, gx = x0 + ix - 1;
    uint4 v = make_uint4(0, 0, 0, 0);
    if ((unsigned)gy < 128u && (unsigned)gx < 128u)
      v = *reinterpret_cast<const uint4*>(
          Wm1t + ((((size_t)b << 14) + (gy << 7) + gx) << 6) + cg * 8);
    *reinterpret_cast<uint4*>(&Xt[pos * 72 + cg * 8]) = v;
  }
  __syncthreads();

  // ---- phase 2: implicit-GEMM MFMA over 18 kc slices ----
  const int wave = tid >> 6, lane = tid & 63;
  const int q = lane >> 4, px16 = lane & 15;

  float4v acc[2][4];
#pragma unroll
  for (int a = 0; a < 2; ++a)
#pragma unroll
    for (int n = 0; n < 4; ++n) acc[a][n] = (float4v){0.f, 0.f, 0.f, 0.f};

  const short8* Ap = reinterpret_cast<const short8*>(Awt);
#pragma unroll
  for (int kc = 0; kc < 18; ++kc) {
    const int t = kc >> 1, h = kc & 1;
    const int dy = t / 3, dx = t - dy * 3;
    short8 af[2];
#pragma unroll
    for (int a = 0; a < 2; ++a)
      af[a] = Ap[kc * 512 + (wave * 2 + a) * 64 + lane];
    short8 bfr[4];
#pragma unroll
    for (int n = 0; n < 4; ++n) {
      int p = n * 16 + px16;                  // pixel in 8x8 tile, row-major 8
      int iy = (p >> 3) + dy, ix = (p & 7) + dx;
      bfr[n] = *reinterpret_cast<const short8*>(
          &Xt[(iy * 10 + ix) * 72 + h * 32 + q * 8]);
    }
#pragma unroll
    for (int a = 0; a < 2; ++a)
#pragma unroll
      for (int n = 0; n < 4; ++n)
        acc[a][n] = __builtin_amdgcn_mfma_f32_16x16x32_bf16(
            af[a], bfr[n], acc[a][n], 0, 0, 0);
  }
  __syncthreads();

  // ---- phase 3: accumulators -> wsm [64 px][101] (pad: stride 101 === 5
  // mod 32, coprime -> phase-4 reads conflict-free; b32 stores) ----
  float* wsm = (float*)smem;
#pragma unroll
  for (int a = 0; a < 2; ++a) {
    int ebase = (wave * 2 + a) * 16 + q * 4;
    if (ebase < 100) {
#pragma unroll
      for (int n = 0; n < 4; ++n) {
        int p = n * 16 + px16;
        float* dst = wsm + p * 101 + ebase;
        dst[0] = acc[a][n][0];
        dst[1] = acc[a][n][1];
        dst[2] = acc[a][n][2];
        dst[3] = acc[a][n][3];
      }
    }
  }
  __syncthreads();

  // ---- phase 4: bias + softmax(25), one (pixel, component) per thread ----
  // wpT row layout (uint [56][64]): row k      = pk2(comp0, comp1) of tap k
  //                                 row 28 + k = pk2(comp2, comp3) of tap k
  // wpT OVERLAYS wsm: all reads complete into regs, barrier, then write.
  {
    const int px = tid & 63, qd = tid >> 6;
    const int rowbase = (qd >> 1) * 28;
    const int half = qd & 1;
    const float* wp = wsm + px * 101 + qd;
    float v[25];
#pragma unroll
    for (int j = 0; j < 25; ++j) v[j] = wp[4 * j] + bias2[4 * j + qd];
    float m = v[0];
#pragma unroll
    for (int j = 1; j < 25; ++j) m = fmaxf(m, v[j]);
    float s = 0.f;
#pragma unroll
    for (int j = 0; j < 25; ++j) { v[j] = __expf(v[j] - m); s += v[j]; }
    float inv = 1.f / s;
    __syncthreads();                           // wsm now dead -> reuse as wpT
    ushort* wpS = (ushort*)smem;               // ushort view of wpT [56][128]
#pragma unroll
    for (int k = 0; k < 25; ++k)
      wpS[(rowbase + k) * 128 + px * 2 + half] = f2bf(v[k] * inv);
  }
  __syncthreads();

  // ---- phase 5: stream wpT out, tile-major + coalesced ----
  {
    const uint4* src = (const uint4*)smem;     // wpT [56][64] uint = 896 uint4
    uint4* dst = reinterpret_cast<uint4*>(
        Wtu + (size_t)((b * 16 + blockIdx.y) * 16 + blockIdx.x) * 3584);
    for (int u = tid; u < 896; u += 256) dst[u] = src[u];
  }
}

// ---------------------------------------------------------------------------
// carafe: apply only (round-0 structure). X staged as bf16 [144 pos][72 ch]
// (20.7 KB LDS) from pixel-major Xb. Weights now read from the TILE-MAJOR
// Wtu: 25 coalesced b32 loads (lane = pixel -> consecutive addresses).
// ---------------------------------------------------------------------------
__global__ __launch_bounds__(256) void carafe_kernel(
    const ushort* __restrict__ Xb, const uint* __restrict__ Wtu,
    float* __restrict__ out) {
  const int tid = threadIdx.x;
  const int b = blockIdx.z;
  const int y0 = blockIdx.y * 8, x0 = blockIdx.x * 8;
  __shared__ __align__(16) ushort xt[144 * 72];

  for (int u = tid; u < 1152; u += 256) {      // 144 pos x 8 ch-groups
    int pos = u >> 3, cg = u & 7;
    int iy = pos / 12, ix = pos - iy * 12;
    int gy = y0 + iy - 2, gx = x0 + ix - 2;
    uint4 v = make_uint4(0, 0, 0, 0);
    if ((unsigned)gy < 128u && (unsigned)gx < 128u)
      v = *reinterpret_cast<const uint4*>(
          Xb + (((size_t)b * 16384 + gy * 128 + gx) << 6) + cg * 8);
    *reinterpret_cast<uint4*>(&xt[pos * 72 + cg * 8]) = v;
  }
  __syncthreads();

  const int p = tid & 63, q = tid >> 6;
  const int r1 = q & 1, cq = q >> 1;
  const int py = p >> 3, px = p & 7;

  const uint* wt = Wtu +
      (size_t)((b * 16 + blockIdx.y) * 16 + blockIdx.x) * 3584 +
      (r1 * 28) * 64 + p;
  uint w[25];
#pragma unroll
  for (int j = 0; j < 25; ++j) w[j] = wt[j * 64];   // coalesced b32 loads

  float2 acc[32];
#pragma unroll
  for (int i = 0; i < 32; ++i) acc[i] = make_float2(0.f, 0.f);

#pragma unroll
  for (int k = 0; k < 25; ++k) {
    const int dy = k / 5, dx = k - dy * 5;
    const ushort* bp = xt + ((py + dy) * 12 + (px + dx)) * 72 + cq * 32;
    float w0 = __uint_as_float(w[k] << 16);
    float w1 = __uint_as_float(w[k] & 0xffff0000u);
#pragma unroll
    for (int j = 0; j < 4; ++j) {
      uint4 xv = *reinterpret_cast<const uint4*>(bp + 8 * j);
      const uint xu[4] = {xv.x, xv.y, xv.z, xv.w};
#pragma unroll
      for (int t = 0; t < 4; ++t) {
        float xlo = __uint_as_float(xu[t] << 16);
        float xhi = __uint_as_float(xu[t] & 0xffff0000u);
        int c = j * 8 + t * 2;
        acc[c].x = fmaf(w0, xlo, acc[c].x);
        acc[c].y = fmaf(w1, xlo, acc[c].y);
        acc[c + 1].x = fmaf(w0, xhi, acc[c + 1].x);
        acc[c + 1].y = fmaf(w1, xhi, acc[c + 1].y);
      }
    }
  }

  int yq = (y0 + py) * 2 + r1;
  int xq = (x0 + px) * 2;
#pragma unroll
  for (int ci = 0; ci < 32; ++ci) {
    int c = cq * 32 + ci;
    *reinterpret_cast<float2*>(
        out + ((size_t)(b * 64 + c) * 256 + yq) * 256 + xq) = acc[ci];
  }
}

// ---------------------------------------------------------------------------
extern "C" void kernel_launch(void* const* d_in, const int* in_sizes, int n_in,
                              void* d_out, int out_size, void* d_ws, size_t ws_size,
                              hipStream_t stream) {
  const float* X          = (const float*)d_in[0];
  const float* comp_w     = (const float*)d_in[1];
  const float* comp_gamma = (const float*)d_in[2];
  const float* comp_beta  = (const float*)d_in[3];
  const float* comp_mean  = (const float*)d_in[4];
  const float* comp_var   = (const float*)d_in[5];
  const float* enc_w      = (const float*)d_in[6];
  const float* enc_b      = (const float*)d_in[7];
  const float* enc_gamma  = (const float*)d_in[8];
  const float* enc_beta   = (const float*)d_in[9];
  const float* enc_mean   = (const float*)d_in[10];
  const float* enc_var    = (const float*)d_in[11];
  float* out = (float*)d_out;

  char* ws = (char*)d_ws;
  ushort* Wm1t  = (ushort*)(ws);                    //  8,388,608 B
  uint*   Wtu   = (uint*)(ws + 8388608);            // 14,680,064 B (tile-major)
  ushort* Xb    = (ushort*)(ws + 23068672);         //  8,388,608 B
  ushort* Awt   = (ushort*)(ws + 31457280);         //    147,456 B
  float*  Wc    = (float*)(ws + 31604736);          //     16,384 B
  float*  bias2 = (float*)(ws + 31621120);          //        512 B
  float*  biasc = (float*)(ws + 31621632);          //        256 B

  xform_kernel<<<53, 256, 0, stream>>>(enc_w, enc_gamma, enc_var,
                                       comp_w, comp_gamma, comp_var,
                                       enc_b, enc_beta, enc_mean,
                                       comp_beta, comp_mean,
                                       Awt, Wc, bias2, biasc);
  compress_kernel<<<1024, 256, 0, stream>>>(X, Wc, biasc, Wm1t, Xb);
  encode_mfma<<<dim3(16, 16, 4), 256, 0, stream>>>(Wm1t, Awt, bias2, Wtu);
  carafe_kernel<<<dim3(16, 16, 4), 256, 0, stream>>>(Xb, Wtu, out);
}